// Round 6
// baseline (401.500 us; speedup 1.0000x reference)
//
#include <hip/hip_runtime.h>

// Problem constants (from reference): B=64, TOPK=2, E=16, C=1024, K=4096
#define BB    64
#define TOPK  2
#define EE    16
#define CC    1024
#define KK    4096

constexpr int RPB  = 8;            // weight rows per block (2 per wave)
constexpr int P    = 8;            // pairs (token,slot) per group
constexpr int KS   = 4;            // K-split (partial sums via atomics)
constexpr int KH   = KK / KS;      // floats per K-slice (=1024)
constexpr int NWIN = KH / 256;     // 256-float windows per slice (=4)

typedef float v4f __attribute__((ext_vector_type(4)));

// ---------------------------------------------------------------------------
// Kernel 1: block 0 builds per-expert routing lists; other blocks initialize
//   out[b,c] = residual[b,c] + sum_s ew[b,s] * bias[idx[b,s], c]
// ---------------------------------------------------------------------------
__global__ __launch_bounds__(256) void route_init(
    const int* __restrict__ idx, const float* __restrict__ ew,
    const float* __restrict__ bias, const float* __restrict__ resid,
    float* __restrict__ out, int* __restrict__ cnt, int* __restrict__ lists)
{
    if (blockIdx.x == 0) {
        __shared__ int scnt[EE];
        if (threadIdx.x < EE) scnt[threadIdx.x] = 0;
        __syncthreads();
        if (threadIdx.x < BB * TOPK) {
            int e = idx[threadIdx.x];
            int pos = atomicAdd(&scnt[e], 1);
            lists[e * 128 + pos] = threadIdx.x;   // pair id = b*TOPK + slot
        }
        __syncthreads();
        if (threadIdx.x < EE) cnt[threadIdx.x] = scnt[threadIdx.x];
    } else {
        int i = (blockIdx.x - 1) * 256 + threadIdx.x;   // i in [0, B*C)
        int b = i >> 10;                                 // C = 1024
        int c = i & (CC - 1);
        float v = resid[i];
#pragma unroll
        for (int s = 0; s < TOPK; s++) {
            int e = idx[b * TOPK + s];
            v += ew[b * TOPK + s] * bias[e * CC + c];
        }
        out[i] = v;
    }
}

// ---------------------------------------------------------------------------
// Kernel 2: grid = E * (C/RPB) * KS = 8192 blocks, 256 threads, 32 KB LDS.
// R5 lesson: register-weights + one-barrier LDS staging is right, but at
// 64 KB LDS only 2 blocks/CU were resident and the phase chain (prefetch ->
// barrier -> compute -> atomics) ran un-overlapped. This round: same
// structure at 1/4 block size -> ~4-5 resident blocks/CU, 32 sequential
// block-rounds/CU, so prefetch bursts of one block overlap compute/atomics
// of its neighbors. Weight slice (2 rows x 1 KB/wave) lives in 32 VGPRs,
// read exactly once; act staged via global_load_lds, one barrier per group.
// ---------------------------------------------------------------------------
__global__ __launch_bounds__(256) void moe_mlp2(
    const float* __restrict__ act, const float* __restrict__ ew,
    const float* __restrict__ W, float* __restrict__ out,
    const int* __restrict__ cnt, const int* __restrict__ lists)
{
    __shared__ float sact[P][KH];   // 8 x 1024 x 4B = 32 KB

    const int bid = blockIdx.x;
    const int e   = bid >> 9;                 // 512 blocks per expert
    const int n   = cnt[e];
    if (n == 0) return;
    const int ct   = (bid >> 2) & 127;        // 128 c-tiles
    const int ks   = bid & 3;
    const int lane = threadIdx.x & 63;
    const int wave = threadIdx.x >> 6;
    const int row0 = ct * RPB + wave * 2;

    // --- weight slice prefetch: 2 rows x 4 nt loads, back-to-back ---
    const v4f* __restrict__ Wb =
        (const v4f*)(W + (size_t)(e * CC + row0) * KK + ks * KH);
    v4f w[2][NWIN];
#pragma unroll
    for (int r = 0; r < 2; r++)
#pragma unroll
        for (int kw = 0; kw < NWIN; kw++)
            w[r][kw] = __builtin_nontemporal_load(
                Wb + (size_t)r * (KK / 4) + kw * 64 + lane);

    for (int g = 0; g < n; g += P) {
        const int np = min(P, n - g);
        if (g) __syncthreads();   // prev group's compute done before re-stage

        // --- async global->LDS staging: chunks of 1 KB (256 floats);
        //     chunk ch -> pair p=ch>>2, quarter q=ch&3; round-robin by wave.
        //     lds dest = wave-uniform base + lane*16 (HW rule). ---
        for (int ch = wave; ch < np * 4; ch += 4) {
            int p  = ch >> 2;
            int q  = ch & 3;
            int pr = lists[e * 128 + g + p];
            const float* gsrc =
                act + (size_t)pr * KK + ks * KH + q * 256 + lane * 4;
            __builtin_amdgcn_global_load_lds(
                (const __attribute__((address_space(1))) void*)gsrc,
                (__attribute__((address_space(3))) void*)&sact[p][q * 256],
                16, 0, 0);
        }
        __syncthreads();   // drains lds staging (and weight prefetch, once)

        float acc[2][P];
#pragma unroll
        for (int r = 0; r < 2; r++)
#pragma unroll
            for (int p = 0; p < P; p++) acc[r][p] = 0.f;

#pragma unroll
        for (int kw = 0; kw < NWIN; kw++) {
            const int fb = kw * 256 + lane * 4;   // float idx within slice
#pragma unroll
            for (int pc = 0; pc < P / 4; pc++) {
                if (pc * 4 < np) {                 // wave-uniform guard
#pragma unroll
                    for (int j = 0; j < 4; j++) {
                        const int p = pc * 4 + j;
                        const v4f a = *(const v4f*)&sact[p][fb];
#pragma unroll
                        for (int r = 0; r < 2; r++)
                            acc[r][p] += w[r][kw].x * a.x + w[r][kw].y * a.y +
                                         w[r][kw].z * a.z + w[r][kw].w * a.w;
                    }
                }
            }
        }

        // wave-wide reduction (64 lanes) then one atomic per (row, pair)
#pragma unroll
        for (int p = 0; p < P; p++) {
            if (p < np) {   // compile-time p => static acc indexing
                float v0 = acc[0][p], v1 = acc[1][p];
#pragma unroll
                for (int off = 32; off > 0; off >>= 1) {
                    v0 += __shfl_down(v0, off, 64);
                    v1 += __shfl_down(v1, off, 64);
                }
                if (lane == 0) {
                    int pr = lists[e * 128 + g + p];
                    float wgt = ew[pr];
                    float* o = out + (pr >> 1) * CC + row0;
                    atomicAdd(o + 0, wgt * v0);
                    atomicAdd(o + 1, wgt * v1);
                }
            }
        }
    }
}

extern "C" void kernel_launch(void* const* d_in, const int* in_sizes, int n_in,
                              void* d_out, int out_size, void* d_ws, size_t ws_size,
                              hipStream_t stream) {
    const float* act   = (const float*)d_in[0];   // [B, TOPK, K]
    const int*   idx   = (const int*)d_in[1];     // [B, TOPK]
    const float* ew    = (const float*)d_in[2];   // [B, TOPK]
    const float* W     = (const float*)d_in[3];   // [E, C, K]
    const float* bias  = (const float*)d_in[4];   // [E, C]
    const float* resid = (const float*)d_in[5];   // [B, C]
    float* out = (float*)d_out;

    int* cnt   = (int*)d_ws;          // 16 ints
    int* lists = (int*)d_ws + 64;     // 16 * 128 ints, 256B-aligned offset

    route_init<<<1 + (BB * CC) / 256, 256, 0, stream>>>(
        idx, ew, bias, resid, out, cnt, lists);
    moe_mlp2<<<EE * (CC / RPB) * KS, 256, 0, stream>>>(
        act, ew, W, out, cnt, lists);
}